// Round 7
// baseline (250.215 us; speedup 1.0000x reference)
//
#include <hip/hip_runtime.h>
#include <math.h>

// B=8, N=2048, Fin=Fout=512, fp32 in/out. bf16 MFMA internally.
// out[n,o] = sum_m exp(adj[n,m]) * (sup[m,o] / D[m]),  D[m] = sum_n exp(adj[n,m])
// p1 is pre-scaled by log2(e) -> adj accumulates in log2 domain -> raw v_exp_f32.
#define BB 8
#define NN 2048
#define FF 512
#define LOG2E 1.4426950408889634f

typedef __attribute__((ext_vector_type(8))) short short8;
typedef __attribute__((ext_vector_type(16))) float floatx16;
typedef __attribute__((ext_vector_type(2))) float float2v;
typedef __attribute__((ext_vector_type(2))) __bf16 bf16x2;

__device__ __forceinline__ unsigned short f2bf(float f) {
    union { float f; unsigned u; } v; v.f = f;
    unsigned r = v.u + 0x7FFFu + ((v.u >> 16) & 1u);
    return (unsigned short)(r >> 16);
}

__device__ __forceinline__ float fexp2(float x) {
#if __has_builtin(__builtin_amdgcn_exp2f)
    return __builtin_amdgcn_exp2f(x);
#else
    return __expf(x * 0.69314718056f);
#endif
}

// packed f32x2 -> bf16x2 (v_cvt_pk_bf16_f32), two scalar 2B stores
__device__ __forceinline__ void pk_store(unsigned short* p0, unsigned short* p1,
                                         float a, float b) {
    union { bf16x2 h; unsigned short s[2]; } u;
    float2v v; v.x = a; v.y = b;
    u.h = __builtin_convertvector(v, bf16x2);
    *p0 = u.s[0]; *p1 = u.s[1];
}

// ---------------------------------------------------------------------------
// BT-GEMM, bf16 32x32x16 MFMA: C[i,j] = sum_k A[i*a_ld+k] * B[j*b_ld+k]
// Tile TI=WI*64 (i) x TJ=WJ*64 (j), NT=WI*WJ*64 threads, BK=64.
// Each wave computes 64x64 as 2x2 frags of 32x32 (acc 16 f32/lane each).
// A/B operand layout: row = lane&31, k = (lane>>5)*8 + elem (m74/m101 family).
// C/D layout: i = (reg&3)+8*(reg>>2)+4*(lane>>5), j = lane&31 (verified m74/m101).
// LDS chunk XOR swizzle slot=kc^(row&7): consecutive-8-lane phase groups hit
// 8 distinct slots -> conflict-free (r5 measured 0).
// modes: 0 = fp32 out + bias[j]; 1 = bf16 out; 2 = bf16 exp2(out) + Dsum[j] colsum
// ---------------------------------------------------------------------------
template<int WI, int WJ>
__global__ __launch_bounds__(WI * WJ * 64) void gemm32(
    const unsigned short* __restrict__ A, const unsigned short* __restrict__ B,
    void* __restrict__ Cv, const float* __restrict__ bias, float* __restrict__ Dsum,
    int K, int a_ld, int b_ld, int ldc,
    long a_batch, long b_batch, long c_batch, int mode)
{
    constexpr int TI = WI * 64, TJ = WJ * 64, NT = WI * WJ * 64;
    constexpr int AISS = TI * 8 / NT;   // 16B chunks per thread for A tile
    constexpr int BISS = TJ * 8 / NT;

    __shared__ __align__(16) unsigned short Alds[TI * 64];
    __shared__ __align__(16) unsigned short Blds[TJ * 64];

    const int tid  = threadIdx.x;
    const int wave = tid >> 6;
    const int lane = tid & 63;
    const int bz   = blockIdx.z;

    const int m0 = blockIdx.y * TI;
    const int n0 = blockIdx.x * TJ;

    const unsigned short* Aptr = A + (long)bz * a_batch + (long)m0 * a_ld;
    const unsigned short* Bptr = B + (long)bz * b_batch + (long)n0 * b_ld;

    const int wi = wave / WJ, wj = wave % WJ;
    const int wm = wi * 64, wn = wj * 64;
    const int l31 = lane & 31;
    const int lh  = lane >> 5;

    // loop-invariant staging offsets (elements) and LDS bases
    int offA[AISS], cbA[AISS], offB[BISS], cbB[BISS];
    #pragma unroll
    for (int s = 0; s < AISS; ++s) {
        const int cbase = s * NT + wave * 64;
        const int c = cbase + lane;
        offA[s] = (c >> 3) * a_ld + (((c & 7) ^ ((c >> 3) & 7)) << 3);
        cbA[s] = cbase * 8;
    }
    #pragma unroll
    for (int s = 0; s < BISS; ++s) {
        const int cbase = s * NT + wave * 64;
        const int c = cbase + lane;
        offB[s] = (c >> 3) * b_ld + (((c & 7) ^ ((c >> 3) & 7)) << 3);
        cbB[s] = cbase * 8;
    }

    floatx16 acc[2][2] = {};

    for (int k0 = 0; k0 < K; k0 += 64) {
        #pragma unroll
        for (int s = 0; s < AISS; ++s)
            __builtin_amdgcn_global_load_lds(
                (const __attribute__((address_space(1))) void*)(Aptr + offA[s]),
                (__attribute__((address_space(3))) void*)&Alds[cbA[s]], 16, 0, 0);
        #pragma unroll
        for (int s = 0; s < BISS; ++s)
            __builtin_amdgcn_global_load_lds(
                (const __attribute__((address_space(1))) void*)(Bptr + offB[s]),
                (__attribute__((address_space(3))) void*)&Blds[cbB[s]], 16, 0, 0);
        Aptr += 64; Bptr += 64;
        __syncthreads();

        #pragma unroll
        for (int ks = 0; ks < 4; ++ks) {
            const int kc = ks * 2 + lh;           // k-chunk 0..7
            const int sw = (kc ^ (lane & 7)) << 3; // slot*8 (row&7 == lane&7)
            short8 af[2], bf[2];
            #pragma unroll
            for (int fi = 0; fi < 2; ++fi)
                af[fi] = *(const short8*)&Alds[(wm + fi * 32 + l31) * 64 + sw];
            #pragma unroll
            for (int fj = 0; fj < 2; ++fj)
                bf[fj] = *(const short8*)&Blds[(wn + fj * 32 + l31) * 64 + sw];
            #pragma unroll
            for (int fi = 0; fi < 2; ++fi)
                #pragma unroll
                for (int fj = 0; fj < 2; ++fj)
                    acc[fi][fj] = __builtin_amdgcn_mfma_f32_32x32x16_bf16(
                        af[fi], bf[fj], acc[fi][fj], 0, 0, 0);
        }
        __syncthreads();
    }

    // epilogue: j spans 32 consecutive lanes -> 64-128B contiguous per store instr
    if (mode == 0) {
        float* Cb = (float*)Cv + (long)bz * c_batch;
        #pragma unroll
        for (int fj = 0; fj < 2; ++fj) {
            const int j = n0 + wn + fj * 32 + l31;
            const float badd = bias ? bias[j] : 0.0f;
            #pragma unroll
            for (int fi = 0; fi < 2; ++fi) {
                const int ib = m0 + wm + fi * 32 + 4 * lh;
                #pragma unroll
                for (int r = 0; r < 16; ++r) {
                    const int i = ib + (r & 3) + 8 * (r >> 2);
                    Cb[(long)i * ldc + j] = acc[fi][fj][r] + badd;
                }
            }
        }
    } else if (mode == 1) {
        unsigned short* Cb = (unsigned short*)Cv + (long)bz * c_batch;
        #pragma unroll
        for (int fj = 0; fj < 2; ++fj) {
            const int j = n0 + wn + fj * 32 + l31;
            #pragma unroll
            for (int fi = 0; fi < 2; ++fi) {
                const int ib = m0 + wm + fi * 32 + 4 * lh;
                #pragma unroll
                for (int r = 0; r < 16; r += 2) {
                    const int i0 = ib + ((r) & 3) + 8 * ((r) >> 2);
                    const int i1 = ib + ((r + 1) & 3) + 8 * ((r + 1) >> 2);
                    pk_store(&Cb[(long)i0 * ldc + j], &Cb[(long)i1 * ldc + j],
                             acc[fi][fj][r], acc[fi][fj][r + 1]);
                }
            }
        }
    } else {
        // mode 2: acc is log2-domain; E = 2^acc bf16; Dsum[j] += column sums.
        unsigned short* Cb = (unsigned short*)Cv + (long)bz * c_batch;
        float* Db = Dsum + (long)bz * NN;
        #pragma unroll
        for (int fi = 0; fi < 2; ++fi)
            #pragma unroll
            for (int fj = 0; fj < 2; ++fj)
                #pragma unroll
                for (int r = 0; r < 16; ++r)
                    acc[fi][fj][r] = fexp2(acc[fi][fj][r]);
        #pragma unroll
        for (int fj = 0; fj < 2; ++fj) {
            const int j = n0 + wn + fj * 32 + l31;
            float csum = 0.f;
            #pragma unroll
            for (int fi = 0; fi < 2; ++fi) {
                const int ib = m0 + wm + fi * 32 + 4 * lh;
                #pragma unroll
                for (int r = 0; r < 16; r += 2) {
                    const int i0 = ib + ((r) & 3) + 8 * ((r) >> 2);
                    const int i1 = ib + ((r + 1) & 3) + 8 * ((r + 1) >> 2);
                    pk_store(&Cb[(long)i0 * ldc + j], &Cb[(long)i1 * ldc + j],
                             acc[fi][fj][r], acc[fi][fj][r + 1]);
                    csum += acc[fi][fj][r] + acc[fi][fj][r + 1];
                }
            }
            csum += __shfl_xor(csum, 32);   // combine the two half-wave row sets
            if (lh == 0) atomicAdd(&Db[j], csum);
        }
    }
}

// fused fp32->bf16 convert for x, w_one (scaled by log2e), w_two
__global__ __launch_bounds__(256) void convert_all(
    const float* __restrict__ x, const float* __restrict__ w1, const float* __restrict__ w2,
    unsigned short* __restrict__ xb, unsigned short* __restrict__ w1b, unsigned short* __restrict__ w2b)
{
    const long NX = (long)BB * NN * FF / 8;
    const long NW = (long)FF * FF / 8;
    long t = (long)blockIdx.x * 256 + threadIdx.x;
    const float* in; unsigned short* out; float sc = 1.0f;
    if (t < NX) { in = x; out = xb; }
    else if (t < NX + NW) { in = w1; out = w1b; t -= NX; sc = LOG2E; }
    else if (t < NX + 2 * NW) { in = w2; out = w2b; t -= NX + NW; }
    else return;
    const long i = t * 8;
    float4 a = *(const float4*)(in + i);
    float4 b = *(const float4*)(in + i + 4);
    union { bf16x2 h[4]; short8 s8; } u;
    float2v v;
    v.x = a.x * sc; v.y = a.y * sc; u.h[0] = __builtin_convertvector(v, bf16x2);
    v.x = a.z * sc; v.y = a.w * sc; u.h[1] = __builtin_convertvector(v, bf16x2);
    v.x = b.x * sc; v.y = b.y * sc; u.h[2] = __builtin_convertvector(v, bf16x2);
    v.x = b.z * sc; v.y = b.w * sc; u.h[3] = __builtin_convertvector(v, bf16x2);
    *(short8*)(out + i) = u.s8;
}

// out[o,f] = bf16(in[f,o]) for dim x dim fp32 (dim % 32 == 0)
__global__ __launch_bounds__(256) void transpose_convert(
    const float* __restrict__ in, unsigned short* __restrict__ out, int dim)
{
    __shared__ float t[32][33];
    const int tx = threadIdx.x & 31, ty = threadIdx.x >> 5;
    const int x0 = blockIdx.x * 32, y0 = blockIdx.y * 32;
    #pragma unroll
    for (int k = 0; k < 32; k += 8)
        t[ty + k][tx] = in[(long)(y0 + ty + k) * dim + x0 + tx];
    __syncthreads();
    #pragma unroll
    for (int k = 0; k < 32; k += 8)
        out[(long)(x0 + ty + k) * dim + y0 + tx] = f2bf(t[tx][ty + k]);
}

__global__ __launch_bounds__(256) void zero_f32(float* __restrict__ p, long n)
{
    long i = (long)blockIdx.x * 256 + threadIdx.x;
    if (i < n) p[i] = 0.0f;
}

// supT[o,m] = bf16( sup[m,o] / D[m] ); sup[m,o] = Call[m*1536 + 1024 + o] (bf16).
__global__ __launch_bounds__(256) void scale_transpose(
    const unsigned short* __restrict__ Call, const float* __restrict__ D,
    unsigned short* __restrict__ supT, int batch0)
{
    __shared__ float t[32][33];
    __shared__ float rD[32];
    const int tx = threadIdx.x & 31, ty = threadIdx.x >> 5;
    const int mt = blockIdx.x * 32, ot = blockIdx.y * 32;
    const int b = batch0 + blockIdx.z;
    const unsigned short* Cb = Call + (long)b * NN * 1536;
    unsigned short* Tb = supT + (long)b * NN * FF;
    if (threadIdx.x < 32) rD[threadIdx.x] = 1.0f / D[(long)b * NN + mt + threadIdx.x];
    __syncthreads();
    #pragma unroll
    for (int k = 0; k < 32; k += 8) {
        unsigned short u = Cb[(long)(mt + ty + k) * 1536 + 1024 + ot + tx];
        union { unsigned uu; float f; } cv; cv.uu = ((unsigned)u) << 16;
        t[ty + k][tx] = cv.f;
    }
    __syncthreads();
    #pragma unroll
    for (int k = 0; k < 32; k += 8)
        Tb[(long)(ot + ty + k) * NN + mt + tx] = f2bf(t[tx][ty + k] * rD[tx]);
}

extern "C" void kernel_launch(void* const* d_in, const int* in_sizes, int n_in,
                              void* d_out, int out_size, void* d_ws, size_t ws_size,
                              hipStream_t stream)
{
    const float* x      = (const float*)d_in[0];
    const float* weight = (const float*)d_in[1];
    const float* bias   = (const float*)d_in[2];
    const float* w_one  = (const float*)d_in[3];
    const float* w_two  = (const float*)d_in[4];
    float* out = (float*)d_out;

    const long NF  = (long)NN * FF;      // 1,048,576
    const long NN2 = (long)NN * NN;      // 4,194,304
    const long CROW = 1536;              // C_all row stride (p1|p2|sup)

    // workspace carve
    char* p = (char*)d_ws;
    unsigned short* xb    = (unsigned short*)p; p += (size_t)BB * NF * 2;          // 16 MB
    unsigned short* Wall  = (unsigned short*)p; p += (size_t)CROW * FF * 2;        // 1.5 MB
    unsigned short* Call  = (unsigned short*)p; p += (size_t)BB * NN * CROW * 2;   // 48 MB
    unsigned short* supT  = (unsigned short*)p; p += (size_t)BB * NF * 2;          // 16 MB
    float*          Dsum  = (float*)p;          p += (size_t)BB * NN * 4;          // 64 KB
    unsigned short* E     = (unsigned short*)p;                                    // 64 MB (full) or 8 MB (batch)
    unsigned short* w1b = Wall;
    unsigned short* w2b = Wall + (size_t)FF * FF;
    unsigned short* wTb = Wall + (size_t)2 * FF * FF;

    const size_t fixed = (size_t)(p - (char*)d_ws);
    const bool full = ws_size >= fixed + (size_t)BB * NN2 * 2;

    dim3 blk(256);

    // 1) converts (w1 pre-scaled by log2e)
    convert_all<<<dim3(4352), blk, 0, stream>>>(x, w_one, w_two, xb, w1b, w2b);
    transpose_convert<<<dim3(FF / 32, FF / 32), blk, 0, stream>>>(weight, wTb, FF);
    zero_f32<<<dim3((BB * NN) / 256), blk, 0, stream>>>(Dsum, BB * NN);

    // 2) Call[n, e] = x[n,:]·Wall[e,:]  — 256(n)x128(e) tiles, 512 thr
    gemm32<4, 2><<<dim3(CROW / 128, NN / 256, BB), dim3(512), 0, stream>>>(
        xb, Wall, Call, nullptr, nullptr, FF,
        FF, FF, (int)CROW, NF, 0, NN * CROW, 1);

    if (full) {
        // 3) E[n,m] = exp2(p1[n,:]·p2[m,:]); Dsum[b,m] += colsums — 256x128, 512 thr
        gemm32<4, 2><<<dim3(NN / 128, NN / 256, BB), dim3(512), 0, stream>>>(
            Call, Call + FF, E, nullptr, Dsum, FF,
            (int)CROW, (int)CROW, NN, NN * CROW, NN * CROW, NN2, 2);
        // 4) supT[o,m] = sup[m,o]/D[m]
        scale_transpose<<<dim3(NN / 32, FF / 32, BB), blk, 0, stream>>>(Call, Dsum, supT, 0);
        // 5) out[n,o] = E[n,:]·supT[o,:] + bias[o] — 128x128, 256 thr (grid 512)
        gemm32<2, 2><<<dim3(FF / 128, NN / 128, BB), blk, 0, stream>>>(
            E, supT, out, bias, nullptr, NN,
            NN, NN, FF, NN2, NF, NF, 0);
    } else {
        for (int b = 0; b < BB; ++b) {
            const unsigned short* Cb = Call + (size_t)b * NN * CROW;
            gemm32<4, 2><<<dim3(NN / 128, NN / 256, 1), dim3(512), 0, stream>>>(
                Cb, Cb + FF, E, nullptr, Dsum + (size_t)b * NN, FF,
                (int)CROW, (int)CROW, NN, 0, 0, 0, 2);
            scale_transpose<<<dim3(NN / 32, FF / 32, 1), blk, 0, stream>>>(Call, Dsum, supT, b);
            gemm32<2, 2><<<dim3(FF / 128, NN / 128, 1), blk, 0, stream>>>(
                E, supT + (size_t)b * NF, out + (size_t)b * NF, bias, nullptr, NN,
                NN, NN, FF, 0, 0, 0, 0);
        }
    }
}

// Round 8
// 242.594 us; speedup vs baseline: 1.0314x; 1.0314x over previous
//
#include <hip/hip_runtime.h>
#include <math.h>

// B=8, N=2048, Fin=Fout=512, fp32 in/out. bf16 MFMA internally.
// out[n,o] = sum_m exp(adj[n,m]) * (sup[m,o] / D[m]),  D[m] = sum_n exp(adj[n,m])
// p1 pre-scaled by log2(e) -> adj in log2 domain -> raw v_exp_f32.
#define BB 8
#define NN 2048
#define FF 512
#define LOG2E 1.4426950408889634f

typedef __attribute__((ext_vector_type(8))) short short8;
typedef __attribute__((ext_vector_type(4))) float floatx4;
typedef __attribute__((ext_vector_type(2))) float float2v;
typedef __attribute__((ext_vector_type(2))) __bf16 bf16x2;

__device__ __forceinline__ unsigned short f2bf(float f) {
    union { float f; unsigned u; } v; v.f = f;
    unsigned r = v.u + 0x7FFFu + ((v.u >> 16) & 1u);
    return (unsigned short)(r >> 16);
}

__device__ __forceinline__ float fexp2(float x) {
#if __has_builtin(__builtin_amdgcn_exp2f)
    return __builtin_amdgcn_exp2f(x);
#else
    return __expf(x * 0.69314718056f);
#endif
}

// packed f32x2 -> bf16x2 (v_cvt_pk_bf16_f32), two scalar 2B stores
__device__ __forceinline__ void pk_store(unsigned short* p0, unsigned short* p1,
                                         float a, float b) {
    union { bf16x2 h; unsigned short s[2]; } u;
    float2v v; v.x = a; v.y = b;
    u.h = __builtin_convertvector(v, bf16x2);
    *p0 = u.s[0]; *p1 = u.s[1];
}

// ---------------------------------------------------------------------------
// BT-GEMM, bf16 16x16x32 MFMA: C[i,j] = sum_k A[i*a_ld+k] * B[j*b_ld+k]
// Block 128x128, BK=64 (32 KB LDS), 128 thr = 2 waves.
// Wave tile 128(i) x 64(j): 8x4 frags -> 24 KB ds_read per 1.05 MFLOP per iter
// (38 B/KFLOP incl. staging vs 64x64's 42+) -> LDS-BW ceiling ~83% of MFMA peak.
// Staging + read swizzle identical to r5/r6 (measured 0 bank conflicts):
// LDS slot (c&7) of row (c>>3) holds global chunk (c&7)^(row&7); reader slot
// = (s*4+quad)^(fl&7), quad-varying across 16-lane groups.
// modes: 0 = fp32 out + bias[j]; 1 = bf16 out; 2 = bf16 exp2(out) + Dsum[j] colsum
// ---------------------------------------------------------------------------
__global__ __launch_bounds__(128, 2) void gemm_bt16(
    const unsigned short* __restrict__ A, const unsigned short* __restrict__ B,
    void* __restrict__ Cv, const float* __restrict__ bias, float* __restrict__ Dsum,
    int K, int a_ld, int b_ld, int ldc,
    long a_batch, long b_batch, long c_batch, int mode)
{
    __shared__ __align__(16) unsigned short Alds[128 * 64];
    __shared__ __align__(16) unsigned short Blds[128 * 64];

    const int tid  = threadIdx.x;
    const int wave = tid >> 6;          // 0..1
    const int lane = tid & 63;
    const int bz   = blockIdx.z;

    const int m0 = blockIdx.y * 128;    // A-row tile (C rows)
    const int n0 = blockIdx.x * 128;    // B-row tile (C cols)

    const unsigned short* Aptr = A + (long)bz * a_batch + (long)m0 * a_ld;
    const unsigned short* Bptr = B + (long)bz * b_batch + (long)n0 * b_ld;

    const int wn   = wave * 64;         // this wave's j-half
    const int fl   = lane & 15;
    const int quad = lane >> 4;

    // loop-invariant staging offsets: 1024 chunks per tile / 128 thr = 8 issues
    int offA[8], offB[8];
    #pragma unroll
    for (int s = 0; s < 8; ++s) {
        const int c = s * 128 + tid;
        const int row = c >> 3;
        const int kq = ((c & 7) ^ (row & 7)) << 3;
        offA[s] = row * a_ld + kq;
        offB[s] = row * b_ld + kq;
    }

    floatx4 acc[8][4] = {};

    for (int k0 = 0; k0 < K; k0 += 64) {
        #pragma unroll
        for (int s = 0; s < 8; ++s) {
            __builtin_amdgcn_global_load_lds(
                (const __attribute__((address_space(1))) void*)(Aptr + offA[s]),
                (__attribute__((address_space(3))) void*)&Alds[(s * 128 + tid - lane) * 8], 16, 0, 0);
            __builtin_amdgcn_global_load_lds(
                (const __attribute__((address_space(1))) void*)(Bptr + offB[s]),
                (__attribute__((address_space(3))) void*)&Blds[(s * 128 + tid - lane) * 8], 16, 0, 0);
        }
        Aptr += 64; Bptr += 64;
        __syncthreads();

        #pragma unroll
        for (int s = 0; s < 2; ++s) {
            const int slot = ((s * 4 + quad) ^ (fl & 7)) * 8;
            short8 af[8], bf[4];
            #pragma unroll
            for (int j = 0; j < 4; ++j)
                bf[j] = *(const short8*)&Blds[(wn + j * 16 + fl) * 64 + slot];
            #pragma unroll
            for (int i = 0; i < 8; ++i)
                af[i] = *(const short8*)&Alds[(i * 16 + fl) * 64 + slot];
            #pragma unroll
            for (int i = 0; i < 8; ++i)
                #pragma unroll
                for (int j = 0; j < 4; ++j)
                    acc[i][j] = __builtin_amdgcn_mfma_f32_16x16x32_bf16(af[i], bf[j], acc[i][j], 0, 0, 0);
        }
        __syncthreads();
    }

    // Epilogue: col(j) = fl across lanes -> 32B contiguous per quad per store.
    if (mode == 0) {
        float* Cb = (float*)Cv + (long)bz * c_batch;
        #pragma unroll
        for (int j = 0; j < 4; ++j) {
            const int ng = n0 + wn + j * 16 + fl;
            const float badd = bias ? bias[ng] : 0.0f;
            #pragma unroll
            for (int i = 0; i < 8; ++i) {
                const int mg = m0 + i * 16 + quad * 4;
                #pragma unroll
                for (int r = 0; r < 4; ++r)
                    Cb[(long)(mg + r) * ldc + ng] = acc[i][j][r] + badd;
            }
        }
    } else if (mode == 1) {
        unsigned short* Cb = (unsigned short*)Cv + (long)bz * c_batch;
        #pragma unroll
        for (int j = 0; j < 4; ++j) {
            const int ng = n0 + wn + j * 16 + fl;
            #pragma unroll
            for (int i = 0; i < 8; ++i) {
                const int mg = m0 + i * 16 + quad * 4;
                pk_store(&Cb[(long)(mg + 0) * ldc + ng], &Cb[(long)(mg + 1) * ldc + ng],
                         acc[i][j][0], acc[i][j][1]);
                pk_store(&Cb[(long)(mg + 2) * ldc + ng], &Cb[(long)(mg + 3) * ldc + ng],
                         acc[i][j][2], acc[i][j][3]);
            }
        }
    } else {
        // mode 2: acc is log2-domain; E = 2^acc bf16; Dsum[col j] += col sums.
        unsigned short* Cb = (unsigned short*)Cv + (long)bz * c_batch;
        float* Db = Dsum + (long)bz * NN;
        #pragma unroll
        for (int i = 0; i < 8; ++i)
            #pragma unroll
            for (int j = 0; j < 4; ++j)
                #pragma unroll
                for (int r = 0; r < 4; ++r)
                    acc[i][j][r] = fexp2(acc[i][j][r]);
        #pragma unroll
        for (int j = 0; j < 4; ++j) {
            const int ng = n0 + wn + j * 16 + fl;
            float csum = 0.f;
            #pragma unroll
            for (int i = 0; i < 8; ++i) {
                const int mg = m0 + i * 16 + quad * 4;
                csum += acc[i][j][0] + acc[i][j][1] + acc[i][j][2] + acc[i][j][3];
                pk_store(&Cb[(long)(mg + 0) * ldc + ng], &Cb[(long)(mg + 1) * ldc + ng],
                         acc[i][j][0], acc[i][j][1]);
                pk_store(&Cb[(long)(mg + 2) * ldc + ng], &Cb[(long)(mg + 3) * ldc + ng],
                         acc[i][j][2], acc[i][j][3]);
            }
            csum += __shfl_xor(csum, 16);
            csum += __shfl_xor(csum, 32);
            if (quad == 0) atomicAdd(&Db[ng], csum);
        }
    }
}

// fused fp32->bf16 convert for x, w_one (scaled by log2e), w_two
__global__ __launch_bounds__(256) void convert_all(
    const float* __restrict__ x, const float* __restrict__ w1, const float* __restrict__ w2,
    unsigned short* __restrict__ xb, unsigned short* __restrict__ w1b, unsigned short* __restrict__ w2b)
{
    const long NX = (long)BB * NN * FF / 8;
    const long NW = (long)FF * FF / 8;
    long t = (long)blockIdx.x * 256 + threadIdx.x;
    const float* in; unsigned short* out; float sc = 1.0f;
    if (t < NX) { in = x; out = xb; }
    else if (t < NX + NW) { in = w1; out = w1b; t -= NX; sc = LOG2E; }
    else if (t < NX + 2 * NW) { in = w2; out = w2b; t -= NX + NW; }
    else return;
    const long i = t * 8;
    float4 a = *(const float4*)(in + i);
    float4 b = *(const float4*)(in + i + 4);
    union { bf16x2 h[4]; short8 s8; } u;
    float2v v;
    v.x = a.x * sc; v.y = a.y * sc; u.h[0] = __builtin_convertvector(v, bf16x2);
    v.x = a.z * sc; v.y = a.w * sc; u.h[1] = __builtin_convertvector(v, bf16x2);
    v.x = b.x * sc; v.y = b.y * sc; u.h[2] = __builtin_convertvector(v, bf16x2);
    v.x = b.z * sc; v.y = b.w * sc; u.h[3] = __builtin_convertvector(v, bf16x2);
    *(short8*)(out + i) = u.s8;
}

// out[o,f] = bf16(in[f,o]) for dim x dim fp32 (dim % 32 == 0)
__global__ __launch_bounds__(256) void transpose_convert(
    const float* __restrict__ in, unsigned short* __restrict__ out, int dim)
{
    __shared__ float t[32][33];
    const int tx = threadIdx.x & 31, ty = threadIdx.x >> 5;
    const int x0 = blockIdx.x * 32, y0 = blockIdx.y * 32;
    #pragma unroll
    for (int k = 0; k < 32; k += 8)
        t[ty + k][tx] = in[(long)(y0 + ty + k) * dim + x0 + tx];
    __syncthreads();
    #pragma unroll
    for (int k = 0; k < 32; k += 8)
        out[(long)(x0 + ty + k) * dim + y0 + tx] = f2bf(t[tx][ty + k]);
}

__global__ __launch_bounds__(256) void zero_f32(float* __restrict__ p, long n)
{
    long i = (long)blockIdx.x * 256 + threadIdx.x;
    if (i < n) p[i] = 0.0f;
}

// supT[o,m] = bf16( sup[m,o] / D[m] ); sup[m,o] = Call[m*1536 + 1024 + o] (bf16).
__global__ __launch_bounds__(256) void scale_transpose(
    const unsigned short* __restrict__ Call, const float* __restrict__ D,
    unsigned short* __restrict__ supT, int batch0)
{
    __shared__ float t[32][33];
    __shared__ float rD[32];
    const int tx = threadIdx.x & 31, ty = threadIdx.x >> 5;
    const int mt = blockIdx.x * 32, ot = blockIdx.y * 32;
    const int b = batch0 + blockIdx.z;
    const unsigned short* Cb = Call + (long)b * NN * 1536;
    unsigned short* Tb = supT + (long)b * NN * FF;
    if (threadIdx.x < 32) rD[threadIdx.x] = 1.0f / D[(long)b * NN + mt + threadIdx.x];
    __syncthreads();
    #pragma unroll
    for (int k = 0; k < 32; k += 8) {
        unsigned short u = Cb[(long)(mt + ty + k) * 1536 + 1024 + ot + tx];
        union { unsigned uu; float f; } cv; cv.uu = ((unsigned)u) << 16;
        t[ty + k][tx] = cv.f;
    }
    __syncthreads();
    #pragma unroll
    for (int k = 0; k < 32; k += 8)
        Tb[(long)(ot + ty + k) * NN + mt + tx] = f2bf(t[tx][ty + k] * rD[tx]);
}

extern "C" void kernel_launch(void* const* d_in, const int* in_sizes, int n_in,
                              void* d_out, int out_size, void* d_ws, size_t ws_size,
                              hipStream_t stream)
{
    const float* x      = (const float*)d_in[0];
    const float* weight = (const float*)d_in[1];
    const float* bias   = (const float*)d_in[2];
    const float* w_one  = (const float*)d_in[3];
    const float* w_two  = (const float*)d_in[4];
    float* out = (float*)d_out;

    const long NF  = (long)NN * FF;      // 1,048,576
    const long NN2 = (long)NN * NN;      // 4,194,304
    const long CROW = 1536;              // C_all row stride (p1|p2|sup)

    // workspace carve
    char* p = (char*)d_ws;
    unsigned short* xb    = (unsigned short*)p; p += (size_t)BB * NF * 2;          // 16 MB
    unsigned short* Wall  = (unsigned short*)p; p += (size_t)CROW * FF * 2;        // 1.5 MB
    unsigned short* Call  = (unsigned short*)p; p += (size_t)BB * NN * CROW * 2;   // 48 MB
    unsigned short* supT  = (unsigned short*)p; p += (size_t)BB * NF * 2;          // 16 MB
    float*          Dsum  = (float*)p;          p += (size_t)BB * NN * 4;          // 64 KB
    unsigned short* E     = (unsigned short*)p;                                    // 64 MB (full) or 8 MB (batch)
    unsigned short* w1b = Wall;
    unsigned short* w2b = Wall + (size_t)FF * FF;
    unsigned short* wTb = Wall + (size_t)2 * FF * FF;

    const size_t fixed = (size_t)(p - (char*)d_ws);
    const bool full = ws_size >= fixed + (size_t)BB * NN2 * 2;

    dim3 blk(256);
    dim3 gblk(128);

    // 1) converts (w1 pre-scaled by log2e)
    convert_all<<<dim3(4352), blk, 0, stream>>>(x, w_one, w_two, xb, w1b, w2b);
    transpose_convert<<<dim3(FF / 32, FF / 32), blk, 0, stream>>>(weight, wTb, FF);
    zero_f32<<<dim3((BB * NN) / 256), blk, 0, stream>>>(Dsum, BB * NN);

    // 2) Call[n, e] = x[n,:]·Wall[e,:]  (i=n rows of xb, j=e rows of Wall)
    gemm_bt16<<<dim3(CROW / 128, NN / 128, BB), gblk, 0, stream>>>(
        xb, Wall, Call, nullptr, nullptr, FF,
        FF, FF, (int)CROW, NF, 0, NN * CROW, 1);

    if (full) {
        // 3) E[n,m] = exp2(p1[n,:]·p2[m,:]); Dsum[b,m] += colsums
        gemm_bt16<<<dim3(NN / 128, NN / 128, BB), gblk, 0, stream>>>(
            Call, Call + FF, E, nullptr, Dsum, FF,
            (int)CROW, (int)CROW, NN, NN * CROW, NN * CROW, NN2, 2);
        // 4) supT[o,m] = sup[m,o]/D[m]
        scale_transpose<<<dim3(NN / 32, FF / 32, BB), blk, 0, stream>>>(Call, Dsum, supT, 0);
        // 5) out[n,o] = E[n,:]·supT[o,:] + bias[o]  (K=2048 -> 32-iter loop)
        gemm_bt16<<<dim3(FF / 128, NN / 128, BB), gblk, 0, stream>>>(
            E, supT, out, bias, nullptr, NN,
            NN, NN, FF, NN2, NF, NF, 0);
    } else {
        for (int b = 0; b < BB; ++b) {
            const unsigned short* Cb = Call + (size_t)b * NN * CROW;
            gemm_bt16<<<dim3(NN / 128, NN / 128, 1), gblk, 0, stream>>>(
                Cb, Cb + FF, E, nullptr, Dsum + (size_t)b * NN, FF,
                (int)CROW, (int)CROW, NN, 0, 0, 0, 2);
            scale_transpose<<<dim3(NN / 32, FF / 32, 1), blk, 0, stream>>>(Call, Dsum, supT, b);
            gemm_bt16<<<dim3(FF / 128, NN / 128, 1), gblk, 0, stream>>>(
                E, supT + (size_t)b * NF, out + (size_t)b * NF, bias, nullptr, NN,
                NN, NN, FF, 0, 0, 0, 0);
        }
    }
}